// Round 7
// baseline (434.393 us; speedup 1.0000x reference)
//
#include <hip/hip_runtime.h>

typedef short short8 __attribute__((ext_vector_type(8)));
typedef short short4v __attribute__((ext_vector_type(4)));
typedef float f32x4 __attribute__((ext_vector_type(4)));

#define MFMA_BF16 __builtin_amdgcn_mfma_f32_16x16x32_bf16

__device__ __forceinline__ unsigned short f2bf(float f) {
  unsigned int u = __float_as_uint(f);
  u += 0x7fffu + ((u >> 16) & 1u);   // round-to-nearest-even
  return (unsigned short)(u >> 16);
}
__device__ __forceinline__ float bf2f(unsigned short u) {
  return __uint_as_float(((unsigned int)u) << 16);
}

// async global->LDS, 16B per lane. LDS dest = wave-uniform base + lane*16.
typedef __attribute__((address_space(1))) const unsigned int as1_u32;
typedef __attribute__((address_space(3))) unsigned int as3_u32;
__device__ __forceinline__ void gld16(const void* g, void* l) {
  __builtin_amdgcn_global_load_lds((as1_u32*)(unsigned long long)g,
                                   (as3_u32*)(unsigned int)(unsigned long long)l,
                                   16, 0, 0);
}

template <int N>
__device__ __forceinline__ void vmwait() {
  if constexpr (N == 0) asm volatile("s_waitcnt vmcnt(0)" ::: "memory");
  else if constexpr (N == 4) asm volatile("s_waitcnt vmcnt(4)" ::: "memory");
  else if constexpr (N == 6) asm volatile("s_waitcnt vmcnt(6)" ::: "memory");
}
__device__ __forceinline__ void barrier_raw() {
  asm volatile("" ::: "memory");
  __builtin_amdgcn_s_barrier();
  asm volatile("" ::: "memory");
}

// ---------------------------------------------------------------------------
// Fused f32 -> bf16 convert: 7 segments selected by blockIdx.y.
// COALESCED: one float4 per thread (16B/lane contiguous reads, 8B/lane
// writes). Was: two float4 at s4[2i],s4[2i+1] -> 32B lane stride = both
// loads half-efficient on a pure-BW kernel.
// ---------------------------------------------------------------------------
struct CvtArgs {
  const float* s[7];
  unsigned short* d[7];
  int n4[7];
};

__global__ __launch_bounds__(256) void cvtall(CvtArgs a) {
  const int seg = blockIdx.y;
  int i = blockIdx.x * 256 + threadIdx.x;
  if (i >= a.n4[seg]) return;
  const float4* s4 = (const float4*)a.s[seg];
  float4 x = s4[i];
  short4v o = {(short)f2bf(x.x), (short)f2bf(x.y), (short)f2bf(x.z), (short)f2bf(x.w)};
  *(short4v*)&a.d[seg][(size_t)i * 4] = o;
}

// ---------------------------------------------------------------------------
// GEMM: C[m,n] = sum_k A[m,k]*W[n,k] + bias[n].  A (M,K) bf16, W (N,K) bf16.
// MF = m-frags per wave (8 -> BM=256, 4 -> BM=128). BN=128, BK=32.
// 256 threads = 4 waves (2M x 2N), wave tile (MF*16) x 64.
// LDS ring-3 -> 2 independent blocks/CU. Phase-split K-step, counted vmcnt,
// XOR swizzle on both sides, setprio on MFMA. (Frozen - register-bound at
// 2 waves/SIMD; acc=128 AGPR + 96 VGPR caps occupancy.)
// M=4096, N=K=2048.
// ---------------------------------------------------------------------------
struct GemmArgs {
  const unsigned short* A[3];
  const unsigned short* W[3];
  const float* bias[3];
  unsigned short* Cb[3];
  float* Cf;
};

template <bool OUTBF, int NZ, int MF>
__global__ __launch_bounds__(256, 2) void gemm_bf16(GemmArgs g) {
  extern __shared__ unsigned short Sh[];
  constexpr int NA = MF / 2;          // A stage instrs per wave per tile
  constexpr int L = NA + 2;           // gld16 per thread per tile
  constexpr int MH = MF / 2;          // m-frags per phase
  constexpr int BOFF = MF * 1024;     // B region offset (elems)
  constexpr int RS = MF * 1024 + 4096;  // ring slot stride (elems)
  const int K = 2048, N = 2048, NT = 64;

  const int B = blockIdx.x;
  int z, bm, bn;
  if constexpr (MF == 8) {
    z = B >> 8;
    const int i = B & 255;
    const int xcd = i & 7, q = i >> 3;      // 16 m-tiles, 16 n-tiles
    bm = (xcd * 2 + (q & 1)) * 256;
    bn = (q >> 1) * 128;
  } else {
    z = 0;
    const int xcd = B & 7, q = B >> 3;      // 32 m-tiles, 16 n-tiles
    bm = (xcd * 4 + (q & 3)) * 128;
    bn = (q >> 2) * 128;
  }

  const unsigned short* __restrict__ A = g.A[z];
  const unsigned short* __restrict__ W = g.W[z];
  const float* __restrict__ bias = g.bias[z];
  unsigned short* __restrict__ Cb = g.Cb[z];

  const int t = threadIdx.x, lane = t & 63, w = t >> 6;
  const int wr = w >> 1, wc = w & 1;
  const int quad = lane >> 4, l16 = lane & 15;

  // staging: each gld16 instr covers 16 rows (4 lanes/row, 16B chunks).
  // source col pre-swizzled so LDS holds chunk p at logical p ^ ((row>>1)&3).
  const int sk = ((lane & 3) * 8) ^ (((lane >> 3) & 3) << 3);
  const int srow = lane >> 2;               // 0..15
  size_t gA[NA], gB[2];
  int lA[NA], lB[2];
  for (int j = 0; j < NA; ++j) {
    gA[j] = (size_t)(bm + w * (MF * 8) + j * 16 + srow) * K + sk;
    lA[j] = (w * (MF * 8) + j * 16) * 32;
  }
  for (int j = 0; j < 2; ++j) {
    gB[j] = (size_t)(bn + w * 32 + j * 16 + srow) * K + sk;
    lB[j] = BOFF + (w * 32 + j * 16) * 32;
  }

  auto STAGE_A = [&](int kq, unsigned short* Ld) {
    for (int j = 0; j < NA; ++j) gld16(A + gA[j] + kq, Ld + lA[j]);
  };
  auto STAGE_B = [&](int kq, unsigned short* Ld) {
    for (int j = 0; j < 2; ++j) gld16(W + gB[j] + kq, Ld + lB[j]);
  };

  // compute-side swizzled read cols (swz bits from l16 only: frag row base
  // is a multiple of 16)
  const int ka = (quad * 8) ^ (((l16 >> 1) & 3) << 3);
  const int raA = (wr * (MF * 16) + l16) * 32 + ka;   // + mt*512
  const int raB = BOFF + (wc * 64 + l16) * 32 + ka;   // + nt*512

  const f32x4 fz = {0.f, 0.f, 0.f, 0.f};
  f32x4 acc[MF][4];
  for (int a = 0; a < MF; ++a)
    for (int b = 0; b < 4; ++b) acc[a][b] = fz;

  unsigned short* cur = Sh;
  unsigned short* nxt = Sh + RS;
  unsigned short* stg = Sh + 2 * RS;

  STAGE_A(0, cur);  STAGE_B(0, cur);
  STAGE_A(32, nxt); STAGE_B(32, nxt);
  vmwait<L>();          // tile 0 landed (tile 1 still in flight)
  barrier_raw();

  for (int tt = 0; tt < NT; ++tt) {
    // ---- phase 0: B-frags + first half of A-frags, stage A of t+2 ----
    short8 af0[MH], bv[4];
#pragma unroll
    for (int mt = 0; mt < MH; ++mt)
      af0[mt] = *(const short8*)&cur[raA + mt * 512];
#pragma unroll
    for (int nt = 0; nt < 4; ++nt)
      bv[nt] = *(const short8*)&cur[raB + nt * 512];
    if (tt + 2 < NT) STAGE_A((tt + 2) * 32, stg);
    barrier_raw();
    __builtin_amdgcn_s_setprio(1);
#pragma unroll
    for (int mt = 0; mt < MH; ++mt)
#pragma unroll
      for (int nt = 0; nt < 4; ++nt)
        acc[mt][nt] = MFMA_BF16(af0[mt], bv[nt], acc[mt][nt], 0, 0, 0);
    __builtin_amdgcn_s_setprio(0);
    barrier_raw();

    // ---- phase 1: second half of A-frags, stage B of t+2, counted vmcnt ----
    short8 af1[MH];
#pragma unroll
    for (int mt = 0; mt < MH; ++mt)
      af1[mt] = *(const short8*)&cur[raA + (MH + mt) * 512];
    if (tt + 2 < NT) STAGE_B((tt + 2) * 32, stg);
    if (tt < NT - 2) vmwait<L>();        // tile tt+1 landed; tt+2 in flight
    else if (tt == NT - 2) vmwait<0>();  // drain for last tile
    barrier_raw();
    __builtin_amdgcn_s_setprio(1);
#pragma unroll
    for (int mt = 0; mt < MH; ++mt)
#pragma unroll
      for (int nt = 0; nt < 4; ++nt)
        acc[MH + mt][nt] = MFMA_BF16(af1[mt], bv[nt], acc[MH + mt][nt], 0, 0, 0);
    __builtin_amdgcn_s_setprio(0);
    barrier_raw();

    unsigned short* tmp = cur; cur = nxt; nxt = stg; stg = tmp;
  }

  for (int mt = 0; mt < MF; ++mt)
    for (int nt = 0; nt < 4; ++nt) {
      int row = bm + wr * (MF * 16) + mt * 16 + quad * 4;
      int col = bn + wc * 64 + nt * 16 + l16;
      float bc = bias[col];
      for (int r2 = 0; r2 < 4; ++r2) {
        float v = acc[mt][nt][r2] + bc;
        if (OUTBF) Cb[(size_t)(row + r2) * N + col] = f2bf(v);
        else       g.Cf[(size_t)(row + r2) * N + col] = v;
      }
    }
}

// ---------------------------------------------------------------------------
// Fused RMSNorm+rotary (Q,K) and V transpose.
// Blocks [0,16384): rmsrope, one wave per (b,h,l) row.
// Blocks [16384,17408): vtrans, Vf bf16 (b,l,e) -> Vt bf16 (b,h,d,l).
// ---------------------------------------------------------------------------
__global__ __launch_bounds__(256) void rmsvt(
    const unsigned short* __restrict__ Qf, const unsigned short* __restrict__ Kf,
    const unsigned short* __restrict__ Vf,
    const float* __restrict__ cosT, const float* __restrict__ sinT,
    unsigned short* __restrict__ Qb, unsigned short* __restrict__ Kb,
    unsigned short* __restrict__ Vt) {
  __shared__ unsigned short Vsh[64 * 136];
  if (blockIdx.x < 16384) {
    const int rid = blockIdx.x * 4 + (threadIdx.x >> 6);
    const int lane = threadIdx.x & 63;
    const int li = rid & 1023;
    const int bh = rid >> 10;
    const int hi = bh & 15, bi = bh >> 4;
    const int src = (bi * 1024 + li) * 2048 + hi * 128;
    const int dst = rid * 128;
    const float c = cosT[li * 64 + lane];
    const float s = sinT[li * 64 + lane];

    float q1 = bf2f(Qf[src + lane]), q2 = bf2f(Qf[src + 64 + lane]);
    float ss = q1 * q1 + q2 * q2;
    for (int off = 32; off; off >>= 1) ss += __shfl_xor(ss, off, 64);
    float r = rsqrtf(ss * (1.f / 128.f) + 1e-6f);
    float qa = q1 * r, qb2 = q2 * r;
    const float qsc = 0.08838834764831845f * 1.4426950408889634f;
    Qb[dst + lane]      = f2bf((qa * c - qb2 * s) * qsc);
    Qb[dst + 64 + lane] = f2bf((qa * s + qb2 * c) * qsc);

    float k1 = bf2f(Kf[src + lane]), k2 = bf2f(Kf[src + 64 + lane]);
    float ks = k1 * k1 + k2 * k2;
    for (int off = 32; off; off >>= 1) ks += __shfl_xor(ks, off, 64);
    float rk = rsqrtf(ks * (1.f / 128.f) + 1e-6f);
    float ka = k1 * rk, kb2 = k2 * rk;
    Kb[dst + lane]      = f2bf(ka * c - kb2 * s);
    Kb[dst + 64 + lane] = f2bf(ka * s + kb2 * c);
  } else {
    const int bid = blockIdx.x - 16384;
    const int t = threadIdx.x;
    const int bh = bid >> 4, l0 = (bid & 15) * 64;
    const int hi = bh & 15, bi = bh >> 4;
    {
      int row = t >> 2, c4 = t & 3;
      const unsigned short* src = &Vf[(size_t)(bi * 1024 + l0 + row) * 2048 + hi * 128];
      for (int i = 0; i < 4; ++i) {
        int chunk = c4 * 4 + i;
        *(int4*)&Vsh[row * 136 + chunk * 8] = *(const int4*)&src[chunk * 8];
      }
    }
    __syncthreads();
    {
      int d = t >> 1, half = t & 1;
      unsigned short* dst = &Vt[(size_t)bh * 131072 + (size_t)d * 1024 + l0 + half * 32];
      for (int g = 0; g < 4; ++g) {
        short8 o;
        for (int j = 0; j < 8; ++j)
          o[j] = (short)Vsh[(half * 32 + g * 8 + j) * 136 + d];
        *(short8*)&dst[g * 8] = o;
      }
    }
  }
}

// ---------------------------------------------------------------------------
// Flash attention, causal, static softmax max, s-SPLIT + balanced pairing.
// v2: 256-row q-tiles, 8 waves x 32 rows (2 row-tiles/wave) -> each bK/bV
// LDS read feeds 2x MFMA. Async gld16 K/V staging into ring-2 LDS, counted
// vmcnt(4), two raw barriers/step. XOR swizzle both sides. Grid 256
// (1 block/CU). Static max => associative partials (unnorm O bf16 + L f32).
// ---------------------------------------------------------------------------
__global__ __launch_bounds__(512, 2) void attn(
    const unsigned short* __restrict__ Qb, const unsigned short* __restrict__ Kb,
    const unsigned short* __restrict__ Vt, unsigned short* __restrict__ Of0,
    unsigned short* __restrict__ Of1, float* __restrict__ Lb) {
  extern __shared__ unsigned short Sh[];
  // layout (elems): K0 [0,8192) K1 [8192,16384) V0 [16384,24576)
  //                 V1 [24576,32768) P [32768 + w*2304)
  const int t = threadIdx.x, lane = t & 63, w = t >> 6;
  const int quad = lane >> 4, l16 = lane & 15;
  const int B = blockIdx.x;
  const int bh = (B & 7) + 8 * ((B >> 3) & 7);
  const int p = (B >> 6) & 1, split = (B >> 7) & 1;
  const unsigned short* Qh = Qb + (size_t)bh * 131072;
  const unsigned short* Kh = Kb + (size_t)bh * 131072;
  const unsigned short* Vh = Vt + (size_t)bh * 131072;
  unsigned short* Oh = (split ? Of1 : Of0) + (size_t)bh * 131072;
  float* Lh = Lb + split * 65536 + bh * 1024;
  unsigned short* Pw = Sh + 32768 + w * 2304;

  const int kc = (lane & 15) * 8;   // K stage: 16B chunk within 128-elem row
  const int vcc = (lane & 7) * 8;   // V stage: 16B chunk within 64-elem row
  const f32x4 fz = {0.f, 0.f, 0.f, 0.f};

  auto STAGE = [&](int s0, int buf) {
    unsigned short* Kd = Sh + buf * 8192;
    unsigned short* Vd = Sh + 16384 + buf * 8192;
#pragma unroll
    for (int j = 0; j < 2; ++j) {
      int row = w * 8 + 4 * j + (lane >> 4);
      int sc = kc ^ ((row & 7) << 3);
      gld16(&Kh[(size_t)(s0 + row) * 128 + sc], &Kd[(w * 8 + 4 * j) * 128]);
    }
#pragma unroll
    for (int j = 0; j < 2; ++j) {
      int row = w * 16 + 8 * j + (lane >> 3);
      int sc = vcc ^ ((row & 7) << 3);
      gld16(&Vh[(size_t)row * 1024 + s0 + sc], &Vd[(w * 16 + 8 * j) * 64]);
    }
  };

  for (int ti = 0; ti < 2; ++ti) {
    const int qt = ti == 0 ? 3 - p : p;
    const int q0 = qt * 256;
    const int qw = q0 + w * 32;           // wave's first q-row

    short8 aQ[2][4];
#pragma unroll
    for (int rt = 0; rt < 2; ++rt) {
      int qr = qw + rt * 16 + l16;
#pragma unroll
      for (int kk = 0; kk < 4; ++kk)
        aQ[rt][kk] = *(const short8*)&Qh[(size_t)qr * 128 + kk * 32 + quad * 8];
    }
    f32x4 oacc[2][8];
#pragma unroll
    for (int rt = 0; rt < 2; ++rt)
#pragma unroll
      for (int i = 0; i < 8; ++i) oacc[rt][i] = fz;
    float Lr[2][4] = {{0.f, 0.f, 0.f, 0.f}, {0.f, 0.f, 0.f, 0.f}};
    const int n = 2 * qt + 2;

    vmwait<0>();        // drain aQ loads + prior O-stores (vmcnt bookkeeping)
    barrier_raw();      // all waves done reading prev buffers
    STAGE(split * 64, 0);

    for (int i = 0; i < n; ++i) {
      const int s0 = (split + 2 * i) * 64;
      barrier_raw();                        // prev compute done (WAR)
      if (i + 1 < n) {
        STAGE((split + 2 * (i + 1)) * 64, (i + 1) & 1);
        vmwait<4>();                        // stage(i) landed; stage(i+1) in flight
      } else {
        vmwait<0>();
      }
      barrier_raw();                        // all waves' stage(i) visible
      const unsigned short* Kl = Sh + (i & 1) * 8192;
      const unsigned short* Vl = Sh + 16384 + (i & 1) * 8192;

      // ---- QK^T (16 bK reads feed 32 MFMA) ----
      f32x4 sfr[2][4];
#pragma unroll
      for (int rt = 0; rt < 2; ++rt)
#pragma unroll
        for (int ni = 0; ni < 4; ++ni) sfr[rt][ni] = fz;
#pragma unroll
      for (int kk = 0; kk < 4; ++kk) {
        short8 bK[4];
#pragma unroll
        for (int ni = 0; ni < 4; ++ni)
          bK[ni] = *(const short8*)&Kl[(ni * 16 + l16) * 128 +
                                       ((kk * 32 + quad * 8) ^ ((l16 & 7) << 3))];
#pragma unroll
        for (int rt = 0; rt < 2; ++rt)
#pragma unroll
          for (int ni = 0; ni < 4; ++ni)
            sfr[rt][ni] = MFMA_BF16(aQ[rt][kk], bK[ni], sfr[rt][ni], 0, 0, 0);
      }

      // ---- softmax (static max), P -> per-wave LDS ----
#pragma unroll
      for (int rt = 0; rt < 2; ++rt) {
        const bool diag = (s0 + 63 > qw + rt * 16);
#pragma unroll
        for (int r = 0; r < 4; ++r) {
          int q = qw + rt * 16 + quad * 4 + r;
          float ps = 0.f;
#pragma unroll
          for (int ni = 0; ni < 4; ++ni) {
            float sv = sfr[rt][ni][r];
            if (diag && (s0 + ni * 16 + l16 > q)) sv = -30000.f;
            float pp = exp2f(sv - 16.5f);
            ps += pp;
            Pw[(rt * 16 + quad * 4 + r) * 72 + ni * 16 + l16] = f2bf(pp);
          }
          ps += __shfl_xor(ps, 1, 64);
          ps += __shfl_xor(ps, 2, 64);
          ps += __shfl_xor(ps, 4, 64);
          ps += __shfl_xor(ps, 8, 64);
          Lr[rt][r] += ps;
        }
      }

      // ---- PV (16 bV reads feed 32 MFMA) ----
#pragma unroll
      for (int kk = 0; kk < 2; ++kk) {
        short8 aP[2];
#pragma unroll
        for (int rt = 0; rt < 2; ++rt)
          aP[rt] = *(const short8*)&Pw[(rt * 16 + l16) * 72 + kk * 32 + quad * 8];
#pragma unroll
        for (int nt = 0; nt < 8; ++nt) {
          short8 bV = *(const short8*)&Vl[(nt * 16 + l16) * 64 +
                                          ((kk * 32 + quad * 8) ^ ((l16 & 7) << 3))];
#pragma unroll
          for (int rt = 0; rt < 2; ++rt)
            oacc[rt][nt] = MFMA_BF16(aP[rt], bV, oacc[rt][nt], 0, 0, 0);
        }
      }
    }

#pragma unroll
    for (int rt = 0; rt < 2; ++rt)
#pragma unroll
      for (int r = 0; r < 4; ++r) {
        int q = qw + rt * 16 + quad * 4 + r;
        size_t base = (size_t)q * 128;
#pragma unroll
        for (int nt = 0; nt < 8; ++nt)
          Oh[base + nt * 16 + l16] = f2bf(oacc[rt][nt][r]);
        if (l16 == 0) Lh[q] = Lr[rt][r];
      }
  }
}

// ---------------------------------------------------------------------------
// Combine split partials + v-projection removal. Out bf16 (b,l,e).
// ---------------------------------------------------------------------------
__global__ __launch_bounds__(256) void vnfix(
    const unsigned short* __restrict__ Of0, const unsigned short* __restrict__ Of1,
    const float* __restrict__ Lb, const unsigned short* __restrict__ Vf,
    unsigned short* __restrict__ Op) {
  const int rid = blockIdx.x * 4 + (threadIdx.x >> 6);
  const int lane = threadIdx.x & 63;
  const int li = rid & 1023;
  const int bh = rid >> 10;
  const int hi = bh & 15, bi = bh >> 4;
  const int src = (bi * 1024 + li) * 2048 + hi * 128;
  float inv = 1.f / (Lb[rid] + Lb[65536 + rid]);
  float o1 = (bf2f(Of0[(size_t)rid * 128 + lane]) + bf2f(Of1[(size_t)rid * 128 + lane])) * inv;
  float o2 = (bf2f(Of0[(size_t)rid * 128 + 64 + lane]) + bf2f(Of1[(size_t)rid * 128 + 64 + lane])) * inv;
  float v1 = bf2f(Vf[src + lane]), v2 = bf2f(Vf[src + 64 + lane]);
  float vv = v1 * v1 + v2 * v2;
  float dd = o1 * v1 + o2 * v2;
  for (int off = 32; off; off >>= 1) {
    vv += __shfl_xor(vv, off, 64);
    dd += __shfl_xor(dd, off, 64);
  }
  float vn = fmaxf(sqrtf(vv), 1e-9f);
  float tc = dd / (vn * vn);
  Op[src + lane]      = f2bf(o1 - tc * v1);
  Op[src + 64 + lane] = f2bf(o2 - tc * v2);
}

// ---------------------------------------------------------------------------
// Workspace map (128 MB), b=4,l=1024,e=2048,h=16,d=128:
//  0-16M   Xq bf16          -> Qb (b,h,l,d) after rmsvt
//  16-32M  Xk bf16          -> Kb
//  32-48M  Xv bf16          -> Vt (b,h,d,l) after rmsvt
//  48-56M  Wqb | 56-64M Wkb -> Opb bf16 (b,l,e) 48-64M after vnfix
//  64-72M  Wvb              -> Lb f32 (512K) by attn
//  72-80M  Wob (live to end)
//  80-96M  Qf bf16          -> Of0 bf16 partial
//  96-112M Kf bf16          -> Of1 bf16 partial
//  112-128M Vf bf16 (live until vnfix)
// ---------------------------------------------------------------------------
extern "C" void kernel_launch(void* const* d_in, const int* in_sizes, int n_in,
                              void* d_out, int out_size, void* d_ws, size_t ws_size,
                              hipStream_t stream) {
  const float* query = (const float*)d_in[0];
  const float* key   = (const float*)d_in[1];
  const float* value = (const float*)d_in[2];
  const float* cosT  = (const float*)d_in[4];
  const float* sinT  = (const float*)d_in[5];
  const float* Wq = (const float*)d_in[6];
  const float* bq = (const float*)d_in[7];
  const float* Wk = (const float*)d_in[8];
  const float* bk = (const float*)d_in[9];
  const float* Wv = (const float*)d_in[10];
  const float* bv = (const float*)d_in[11];
  const float* Wo = (const float*)d_in[12];
  const float* bo = (const float*)d_in[13];
  float* out = (float*)d_out;

  char* ws = (char*)d_ws;
  const size_t MB = 1048576;
  unsigned short* Xq  = (unsigned short*)(ws);
  unsigned short* Xk  = (unsigned short*)(ws + 16 * MB);
  unsigned short* Xv  = (unsigned short*)(ws + 32 * MB);
  unsigned short* Wqb = (unsigned short*)(ws + 48 * MB);
  unsigned short* Wkb = (unsigned short*)(ws + 56 * MB);
  unsigned short* Wvb = (unsigned short*)(ws + 64 * MB);
  unsigned short* Wob = (unsigned short*)(ws + 72 * MB);
  unsigned short* Qf  = (unsigned short*)(ws + 80 * MB);
  unsigned short* Kf  = (unsigned short*)(ws + 96 * MB);
  unsigned short* Vf  = (unsigned short*)(ws + 112 * MB);
  unsigned short* Qbb = Xq;
  unsigned short* Kbb = Xk;
  unsigned short* Vtb = Xv;
  unsigned short* Of0 = Qf;
  unsigned short* Of1 = Kf;
  float*          Lbp = (float*)(ws + 64 * MB);
  unsigned short* Opb = (unsigned short*)(ws + 48 * MB);

  // 1. converts (coalesced: one float4/thread)
  CvtArgs ca;
  ca.s[0] = query; ca.d[0] = Xq;  ca.n4[0] = 2097152;
  ca.s[1] = key;   ca.d[1] = Xk;  ca.n4[1] = 2097152;
  ca.s[2] = value; ca.d[2] = Xv;  ca.n4[2] = 2097152;
  ca.s[3] = Wq;    ca.d[3] = Wqb; ca.n4[3] = 1048576;
  ca.s[4] = Wk;    ca.d[4] = Wkb; ca.n4[4] = 1048576;
  ca.s[5] = Wv;    ca.d[5] = Wvb; ca.n4[5] = 1048576;
  ca.s[6] = Wo;    ca.d[6] = Wob; ca.n4[6] = 1048576;
  cvtall<<<dim3(8192, 7), 256, 0, stream>>>(ca);

  // 2. Q,K,V projections: BM=256 (MF=8), 768 blocks of 256 thr, 2 blocks/CU
  GemmArgs gp;
  gp.A[0] = Xq;  gp.A[1] = Xk;  gp.A[2] = Xv;
  gp.W[0] = Wqb; gp.W[1] = Wkb; gp.W[2] = Wvb;
  gp.bias[0] = bq; gp.bias[1] = bk; gp.bias[2] = bv;
  gp.Cb[0] = Qf; gp.Cb[1] = Kf; gp.Cb[2] = Vf;
  gp.Cf = nullptr;
  gemm_bf16<true, 3, 8><<<768, 256, 73728, stream>>>(gp);

  // 3. rmsnorm+rope + V transpose (one dispatch)
  rmsvt<<<17408, 256, 0, stream>>>(Qf, Kf, Vf, cosT, sinT, Qbb, Kbb, Vtb);

  // 4. attention v2: 256 blocks (1/CU), 512 thr, 100KB LDS ring-2
  attn<<<256, 512, 102400, stream>>>(Qbb, Kbb, Vtb, Of0, Of1, Lbp);

  // 5. combine + v-projection removal
  vnfix<<<16384, 256, 0, stream>>>(Of0, Of1, Lbp, Vf, Opb);

  // 6. output projection: BM=256 (MF=8), 256 blocks of 256 thr
  GemmArgs go;
  go.A[0] = Opb; go.A[1] = nullptr; go.A[2] = nullptr;
  go.W[0] = Wob; go.W[1] = nullptr; go.W[2] = nullptr;
  go.bias[0] = bo; go.bias[1] = nullptr; go.bias[2] = nullptr;
  go.Cb[0] = nullptr; go.Cb[1] = nullptr; go.Cb[2] = nullptr;
  go.Cf = out;
  gemm_bf16<false, 1, 8><<<256, 256, 73728, stream>>>(go);
}

// Round 8
// 412.355 us; speedup vs baseline: 1.0534x; 1.0534x over previous
//
#include <hip/hip_runtime.h>

typedef short short8 __attribute__((ext_vector_type(8)));
typedef short short4v __attribute__((ext_vector_type(4)));
typedef float f32x4 __attribute__((ext_vector_type(4)));

#define MFMA_BF16 __builtin_amdgcn_mfma_f32_16x16x32_bf16

__device__ __forceinline__ unsigned short f2bf(float f) {
  unsigned int u = __float_as_uint(f);
  u += 0x7fffu + ((u >> 16) & 1u);   // round-to-nearest-even
  return (unsigned short)(u >> 16);
}
__device__ __forceinline__ float bf2f(unsigned short u) {
  return __uint_as_float(((unsigned int)u) << 16);
}

// async global->LDS, 16B per lane. LDS dest = wave-uniform base + lane*16.
typedef __attribute__((address_space(1))) const unsigned int as1_u32;
typedef __attribute__((address_space(3))) unsigned int as3_u32;
__device__ __forceinline__ void gld16(const void* g, void* l) {
  __builtin_amdgcn_global_load_lds((as1_u32*)(unsigned long long)g,
                                   (as3_u32*)(unsigned int)(unsigned long long)l,
                                   16, 0, 0);
}

template <int N>
__device__ __forceinline__ void vmwait() {
  if constexpr (N == 0) asm volatile("s_waitcnt vmcnt(0)" ::: "memory");
  else if constexpr (N == 4) asm volatile("s_waitcnt vmcnt(4)" ::: "memory");
  else if constexpr (N == 6) asm volatile("s_waitcnt vmcnt(6)" ::: "memory");
}
__device__ __forceinline__ void barrier_raw() {
  asm volatile("" ::: "memory");
  __builtin_amdgcn_s_barrier();
  asm volatile("" ::: "memory");
}

// ---------------------------------------------------------------------------
// Fused f32 -> bf16 convert: 7 segments selected by blockIdx.y.
// ---------------------------------------------------------------------------
struct CvtArgs {
  const float* s[7];
  unsigned short* d[7];
  int n4[7];
};

__global__ __launch_bounds__(256) void cvtall(CvtArgs a) {
  const int seg = blockIdx.y;
  int i = blockIdx.x * 256 + threadIdx.x;
  if (i >= a.n4[seg]) return;
  const float4* s4 = (const float4*)a.s[seg];
  float4 x = s4[i];
  short4v o = {(short)f2bf(x.x), (short)f2bf(x.y), (short)f2bf(x.z), (short)f2bf(x.w)};
  *(short4v*)&a.d[seg][(size_t)i * 4] = o;
}

// ---------------------------------------------------------------------------
// GEMM: C[m,n] = sum_k A[m,k]*W[n,k] + bias[n].  A (M,K) bf16, W (N,K) bf16.
// MF = m-frags per wave (8 -> BM=256, 4 -> BM=128). BN=128, BK=32.
// 256 threads = 4 waves (2M x 2N), wave tile (MF*16) x 64.
// LDS ring-3 -> 2 independent blocks/CU. Phase-split K-step, counted vmcnt,
// XOR swizzle on both sides, setprio on MFMA. (Frozen - register-bound at
// 2 waves/SIMD; acc=128 AGPR + 96 VGPR caps occupancy.)
// M=4096, N=K=2048.
// ---------------------------------------------------------------------------
struct GemmArgs {
  const unsigned short* A[3];
  const unsigned short* W[3];
  const float* bias[3];
  unsigned short* Cb[3];
  float* Cf;
};

template <bool OUTBF, int NZ, int MF>
__global__ __launch_bounds__(256, 2) void gemm_bf16(GemmArgs g) {
  extern __shared__ unsigned short Sh[];
  constexpr int NA = MF / 2;          // A stage instrs per wave per tile
  constexpr int L = NA + 2;           // gld16 per thread per tile
  constexpr int MH = MF / 2;          // m-frags per phase
  constexpr int BOFF = MF * 1024;     // B region offset (elems)
  constexpr int RS = MF * 1024 + 4096;  // ring slot stride (elems)
  const int K = 2048, N = 2048, NT = 64;

  const int B = blockIdx.x;
  int z, bm, bn;
  if constexpr (MF == 8) {
    z = B >> 8;
    const int i = B & 255;
    const int xcd = i & 7, q = i >> 3;      // 16 m-tiles, 16 n-tiles
    bm = (xcd * 2 + (q & 1)) * 256;
    bn = (q >> 1) * 128;
  } else {
    z = 0;
    const int xcd = B & 7, q = B >> 3;      // 32 m-tiles, 16 n-tiles
    bm = (xcd * 4 + (q & 3)) * 128;
    bn = (q >> 2) * 128;
  }

  const unsigned short* __restrict__ A = g.A[z];
  const unsigned short* __restrict__ W = g.W[z];
  const float* __restrict__ bias = g.bias[z];
  unsigned short* __restrict__ Cb = g.Cb[z];

  const int t = threadIdx.x, lane = t & 63, w = t >> 6;
  const int wr = w >> 1, wc = w & 1;
  const int quad = lane >> 4, l16 = lane & 15;

  // staging: each gld16 instr covers 16 rows (4 lanes/row, 16B chunks).
  // source col pre-swizzled so LDS holds chunk p at logical p ^ ((row>>1)&3).
  const int sk = ((lane & 3) * 8) ^ (((lane >> 3) & 3) << 3);
  const int srow = lane >> 2;               // 0..15
  size_t gA[NA], gB[2];
  int lA[NA], lB[2];
  for (int j = 0; j < NA; ++j) {
    gA[j] = (size_t)(bm + w * (MF * 8) + j * 16 + srow) * K + sk;
    lA[j] = (w * (MF * 8) + j * 16) * 32;
  }
  for (int j = 0; j < 2; ++j) {
    gB[j] = (size_t)(bn + w * 32 + j * 16 + srow) * K + sk;
    lB[j] = BOFF + (w * 32 + j * 16) * 32;
  }

  auto STAGE_A = [&](int kq, unsigned short* Ld) {
    for (int j = 0; j < NA; ++j) gld16(A + gA[j] + kq, Ld + lA[j]);
  };
  auto STAGE_B = [&](int kq, unsigned short* Ld) {
    for (int j = 0; j < 2; ++j) gld16(W + gB[j] + kq, Ld + lB[j]);
  };

  // compute-side swizzled read cols (swz bits from l16 only: frag row base
  // is a multiple of 16)
  const int ka = (quad * 8) ^ (((l16 >> 1) & 3) << 3);
  const int raA = (wr * (MF * 16) + l16) * 32 + ka;   // + mt*512
  const int raB = BOFF + (wc * 64 + l16) * 32 + ka;   // + nt*512

  const f32x4 fz = {0.f, 0.f, 0.f, 0.f};
  f32x4 acc[MF][4];
  for (int a = 0; a < MF; ++a)
    for (int b = 0; b < 4; ++b) acc[a][b] = fz;

  unsigned short* cur = Sh;
  unsigned short* nxt = Sh + RS;
  unsigned short* stg = Sh + 2 * RS;

  STAGE_A(0, cur);  STAGE_B(0, cur);
  STAGE_A(32, nxt); STAGE_B(32, nxt);
  vmwait<L>();          // tile 0 landed (tile 1 still in flight)
  barrier_raw();

  for (int tt = 0; tt < NT; ++tt) {
    // ---- phase 0: B-frags + first half of A-frags, stage A of t+2 ----
    short8 af0[MH], bv[4];
#pragma unroll
    for (int mt = 0; mt < MH; ++mt)
      af0[mt] = *(const short8*)&cur[raA + mt * 512];
#pragma unroll
    for (int nt = 0; nt < 4; ++nt)
      bv[nt] = *(const short8*)&cur[raB + nt * 512];
    if (tt + 2 < NT) STAGE_A((tt + 2) * 32, stg);
    barrier_raw();
    __builtin_amdgcn_s_setprio(1);
#pragma unroll
    for (int mt = 0; mt < MH; ++mt)
#pragma unroll
      for (int nt = 0; nt < 4; ++nt)
        acc[mt][nt] = MFMA_BF16(af0[mt], bv[nt], acc[mt][nt], 0, 0, 0);
    __builtin_amdgcn_s_setprio(0);
    barrier_raw();

    // ---- phase 1: second half of A-frags, stage B of t+2, counted vmcnt ----
    short8 af1[MH];
#pragma unroll
    for (int mt = 0; mt < MH; ++mt)
      af1[mt] = *(const short8*)&cur[raA + (MH + mt) * 512];
    if (tt + 2 < NT) STAGE_B((tt + 2) * 32, stg);
    if (tt < NT - 2) vmwait<L>();        // tile tt+1 landed; tt+2 in flight
    else if (tt == NT - 2) vmwait<0>();  // drain for last tile
    barrier_raw();
    __builtin_amdgcn_s_setprio(1);
#pragma unroll
    for (int mt = 0; mt < MH; ++mt)
#pragma unroll
      for (int nt = 0; nt < 4; ++nt)
        acc[MH + mt][nt] = MFMA_BF16(af1[mt], bv[nt], acc[MH + mt][nt], 0, 0, 0);
    __builtin_amdgcn_s_setprio(0);
    barrier_raw();

    unsigned short* tmp = cur; cur = nxt; nxt = stg; stg = tmp;
  }

  for (int mt = 0; mt < MF; ++mt)
    for (int nt = 0; nt < 4; ++nt) {
      int row = bm + wr * (MF * 16) + mt * 16 + quad * 4;
      int col = bn + wc * 64 + nt * 16 + l16;
      float bc = bias[col];
      for (int r2 = 0; r2 < 4; ++r2) {
        float v = acc[mt][nt][r2] + bc;
        if (OUTBF) Cb[(size_t)(row + r2) * N + col] = f2bf(v);
        else       g.Cf[(size_t)(row + r2) * N + col] = v;
      }
    }
}

// ---------------------------------------------------------------------------
// Fused RMSNorm+rotary (Q,K) and V transpose.
// Blocks [0,16384): rmsrope, one wave per (b,h,l) row.
// Blocks [16384,17408): vtrans, Vf bf16 (b,l,e) -> Vt bf16 (b,h,d,l).
// ---------------------------------------------------------------------------
__global__ __launch_bounds__(256) void rmsvt(
    const unsigned short* __restrict__ Qf, const unsigned short* __restrict__ Kf,
    const unsigned short* __restrict__ Vf,
    const float* __restrict__ cosT, const float* __restrict__ sinT,
    unsigned short* __restrict__ Qb, unsigned short* __restrict__ Kb,
    unsigned short* __restrict__ Vt) {
  __shared__ unsigned short Vsh[64 * 136];
  if (blockIdx.x < 16384) {
    const int rid = blockIdx.x * 4 + (threadIdx.x >> 6);
    const int lane = threadIdx.x & 63;
    const int li = rid & 1023;
    const int bh = rid >> 10;
    const int hi = bh & 15, bi = bh >> 4;
    const int src = (bi * 1024 + li) * 2048 + hi * 128;
    const int dst = rid * 128;
    const float c = cosT[li * 64 + lane];
    const float s = sinT[li * 64 + lane];

    float q1 = bf2f(Qf[src + lane]), q2 = bf2f(Qf[src + 64 + lane]);
    float ss = q1 * q1 + q2 * q2;
    for (int off = 32; off; off >>= 1) ss += __shfl_xor(ss, off, 64);
    float r = rsqrtf(ss * (1.f / 128.f) + 1e-6f);
    float qa = q1 * r, qb2 = q2 * r;
    const float qsc = 0.08838834764831845f * 1.4426950408889634f;
    Qb[dst + lane]      = f2bf((qa * c - qb2 * s) * qsc);
    Qb[dst + 64 + lane] = f2bf((qa * s + qb2 * c) * qsc);

    float k1 = bf2f(Kf[src + lane]), k2 = bf2f(Kf[src + 64 + lane]);
    float ks = k1 * k1 + k2 * k2;
    for (int off = 32; off; off >>= 1) ks += __shfl_xor(ks, off, 64);
    float rk = rsqrtf(ks * (1.f / 128.f) + 1e-6f);
    float ka = k1 * rk, kb2 = k2 * rk;
    Kb[dst + lane]      = f2bf(ka * c - kb2 * s);
    Kb[dst + 64 + lane] = f2bf(ka * s + kb2 * c);
  } else {
    const int bid = blockIdx.x - 16384;
    const int t = threadIdx.x;
    const int bh = bid >> 4, l0 = (bid & 15) * 64;
    const int hi = bh & 15, bi = bh >> 4;
    {
      int row = t >> 2, c4 = t & 3;
      const unsigned short* src = &Vf[(size_t)(bi * 1024 + l0 + row) * 2048 + hi * 128];
      for (int i = 0; i < 4; ++i) {
        int chunk = c4 * 4 + i;
        *(int4*)&Vsh[row * 136 + chunk * 8] = *(const int4*)&src[chunk * 8];
      }
    }
    __syncthreads();
    {
      int d = t >> 1, half = t & 1;
      unsigned short* dst = &Vt[(size_t)bh * 131072 + (size_t)d * 1024 + l0 + half * 32];
      for (int g = 0; g < 4; ++g) {
        short8 o;
        for (int j = 0; j < 8; ++j)
          o[j] = (short)Vsh[(half * 32 + g * 8 + j) * 136 + d];
        *(short8*)&dst[g * 8] = o;
      }
    }
  }
}

// ---------------------------------------------------------------------------
// Flash attention v3, causal, static softmax max, NO s-split.
// 256 blocks (1/CU): bh = XCD-local (B&63), p = B>>6 in 0..3 -> balanced
// causal pair of 128-row q-tiles (7-p, p), 20 s-steps total per block.
// L complete in-block -> epilogue normalizes AND applies v-projection
// removal in-register, writing final Op (b,l,e) directly. vnfix kernel and
// the 64MB Of0/Of1 HBM roundtrip are eliminated.
// Async gld16 K/V staging into ring-2 LDS, counted vmcnt(4), two raw
// barriers/step, XOR swizzle both sides. Causal mask hoisted: only the last
// 2 steps of each q-tile (i >= 2*qt) pay mask arithmetic.
// LDS: K ring 2x16KB | V ring 2x16KB | P 8x(16x72) = 82KB dynamic.
// ---------------------------------------------------------------------------
__global__ __launch_bounds__(512, 2) void attn(
    const unsigned short* __restrict__ Qb, const unsigned short* __restrict__ Kb,
    const unsigned short* __restrict__ Vt, const unsigned short* __restrict__ Vf,
    unsigned short* __restrict__ Op) {
  extern __shared__ unsigned short Sh[];
  // layout (elems): K0 [0,8192) K1 [8192,16384) V0 [16384,24576)
  //                 V1 [24576,32768) P [32768 + w*1152)
  const int t = threadIdx.x, lane = t & 63, w = t >> 6;
  const int quad = lane >> 4, l16 = lane & 15;
  const int B = blockIdx.x;
  const int bh = (B & 7) + 8 * ((B >> 3) & 7);
  const int p = B >> 6;                 // 0..3 -> q-tile pair (7-p, p)
  const int hi = bh & 15, bi = bh >> 4;
  const unsigned short* Qh = Qb + (size_t)bh * 131072;
  const unsigned short* Kh = Kb + (size_t)bh * 131072;
  const unsigned short* Vh = Vt + (size_t)bh * 131072;
  unsigned short* Pw = Sh + 32768 + w * 1152;

  const int kc = (lane & 15) * 8;   // K stage: 16B chunk within 128-elem row
  const int vcc = (lane & 7) * 8;   // V stage: 16B chunk within 64-elem row
  const f32x4 fz = {0.f, 0.f, 0.f, 0.f};

  auto STAGE = [&](int s0, int buf) {
    unsigned short* Kd = Sh + buf * 8192;
    unsigned short* Vd = Sh + 16384 + buf * 8192;
#pragma unroll
    for (int j = 0; j < 2; ++j) {
      int row = w * 8 + 4 * j + (lane >> 4);
      int sc = kc ^ ((row & 7) << 3);
      gld16(&Kh[(size_t)(s0 + row) * 128 + sc], &Kd[(w * 8 + 4 * j) * 128]);
    }
#pragma unroll
    for (int j = 0; j < 2; ++j) {
      int row = w * 16 + 8 * j + (lane >> 3);
      int sc = vcc ^ ((row & 7) << 3);
      gld16(&Vh[(size_t)row * 1024 + s0 + sc], &Vd[(w * 16 + 8 * j) * 64]);
    }
  };

  for (int ti = 0; ti < 2; ++ti) {
    const int qt = ti == 0 ? 7 - p : p;
    const int qw = qt * 128 + w * 16;     // wave's first q-row

    short8 aQ[4];
    {
      int qr = qw + l16;
#pragma unroll
      for (int kk = 0; kk < 4; ++kk)
        aQ[kk] = *(const short8*)&Qh[(size_t)qr * 128 + kk * 32 + quad * 8];
    }
    f32x4 oacc[8];
#pragma unroll
    for (int i = 0; i < 8; ++i) oacc[i] = fz;
    float Lr[4] = {0.f, 0.f, 0.f, 0.f};
    const int n = 2 * qt + 2;

    vmwait<0>();        // drain aQ loads + prior epilogue stores
    barrier_raw();      // all waves done reading prev ring buffers
    STAGE(0, 0);

    for (int i = 0; i < n; ++i) {
      const int s0 = i * 64;
      barrier_raw();                        // prev compute done (WAR)
      if (i + 1 < n) {
        STAGE((i + 1) * 64, (i + 1) & 1);
        vmwait<4>();                        // stage(i) landed; stage(i+1) in flight
      } else {
        vmwait<0>();
      }
      barrier_raw();                        // all waves' stage(i) visible
      const unsigned short* Kl = Sh + (i & 1) * 8192;
      const unsigned short* Vl = Sh + 16384 + (i & 1) * 8192;

      // ---- QK^T ----
      f32x4 sfr[4];
#pragma unroll
      for (int j = 0; j < 4; ++j) sfr[j] = fz;
#pragma unroll
      for (int kk = 0; kk < 4; ++kk)
#pragma unroll
        for (int ni = 0; ni < 4; ++ni) {
          short8 bK = *(const short8*)&Kl[(ni * 16 + l16) * 128 +
                                          ((kk * 32 + quad * 8) ^ ((l16 & 7) << 3))];
          sfr[ni] = MFMA_BF16(aQ[kk], bK, sfr[ni], 0, 0, 0);
        }

      // ---- softmax (static max), P -> per-wave LDS ----
      if (i >= 2 * qt) {                    // diagonal steps: mask needed
#pragma unroll
        for (int r = 0; r < 4; ++r) {
          int q = qw + quad * 4 + r;
          float ps = 0.f;
#pragma unroll
          for (int ni = 0; ni < 4; ++ni) {
            float sv = sfr[ni][r];
            if (s0 + ni * 16 + l16 > q) sv = -30000.f;
            float pp = exp2f(sv - 16.5f);
            ps += pp;
            Pw[(quad * 4 + r) * 72 + ni * 16 + l16] = f2bf(pp);
          }
          ps += __shfl_xor(ps, 1, 64);
          ps += __shfl_xor(ps, 2, 64);
          ps += __shfl_xor(ps, 4, 64);
          ps += __shfl_xor(ps, 8, 64);
          Lr[r] += ps;
        }
      } else {                              // interior steps: mask-free
#pragma unroll
        for (int r = 0; r < 4; ++r) {
          float ps = 0.f;
#pragma unroll
          for (int ni = 0; ni < 4; ++ni) {
            float pp = exp2f(sfr[ni][r] - 16.5f);
            ps += pp;
            Pw[(quad * 4 + r) * 72 + ni * 16 + l16] = f2bf(pp);
          }
          ps += __shfl_xor(ps, 1, 64);
          ps += __shfl_xor(ps, 2, 64);
          ps += __shfl_xor(ps, 4, 64);
          ps += __shfl_xor(ps, 8, 64);
          Lr[r] += ps;
        }
      }

      // ---- PV ----
#pragma unroll
      for (int kk = 0; kk < 2; ++kk) {
        short8 aP = *(const short8*)&Pw[l16 * 72 + kk * 32 + quad * 8];
#pragma unroll
        for (int nt = 0; nt < 8; ++nt) {
          short8 bV = *(const short8*)&Vl[(nt * 16 + l16) * 64 +
                                          ((kk * 32 + quad * 8) ^ ((l16 & 7) << 3))];
          oacc[nt] = MFMA_BF16(aP, bV, oacc[nt], 0, 0, 0);
        }
      }
    }

    // ---- epilogue: normalize + v-projection removal, write Op (b,l,e) ----
#pragma unroll
    for (int r = 0; r < 4; ++r) {
      int q = qw + quad * 4 + r;
      float inv = 1.f / Lr[r];
      const unsigned short* vrow = &Vf[((size_t)(bi * 1024 + q)) * 2048 + hi * 128];
      float vr[8], vv = 0.f, dd = 0.f;
#pragma unroll
      for (int nt = 0; nt < 8; ++nt) {
        vr[nt] = bf2f(vrow[nt * 16 + l16]);
        vv += vr[nt] * vr[nt];
        dd += oacc[nt][r] * vr[nt];
      }
#pragma unroll
      for (int off = 1; off < 16; off <<= 1) {
        vv += __shfl_xor(vv, off, 64);
        dd += __shfl_xor(dd, off, 64);
      }
      dd *= inv;                               // (o/L) . v
      float tc = dd / fmaxf(vv, 1e-18f);       // == dd / max(|v|,1e-9)^2
      unsigned short* orow = &Op[((size_t)(bi * 1024 + q)) * 2048 + hi * 128];
#pragma unroll
      for (int nt = 0; nt < 8; ++nt)
        orow[nt * 16 + l16] = f2bf(oacc[nt][r] * inv - tc * vr[nt]);
    }
  }
}

// ---------------------------------------------------------------------------
// Workspace map (128 MB), b=4,l=1024,e=2048,h=16,d=128:
//  0-16M   Xq bf16          -> Qb (b,h,l,d) after rmsvt
//  16-32M  Xk bf16          -> Kb
//  32-48M  Xv bf16          -> Vt (b,h,d,l) after rmsvt
//  48-56M  Wqb | 56-64M Wkb -> Opb bf16 (b,l,e) 48-64M after attn
//  64-72M  Wvb
//  72-80M  Wob (live to end)
//  80-96M  Qf bf16 (dead after rmsvt)
//  96-112M Kf bf16 (dead after rmsvt)
//  112-128M Vf bf16 (live until attn epilogue)
// ---------------------------------------------------------------------------
extern "C" void kernel_launch(void* const* d_in, const int* in_sizes, int n_in,
                              void* d_out, int out_size, void* d_ws, size_t ws_size,
                              hipStream_t stream) {
  const float* query = (const float*)d_in[0];
  const float* key   = (const float*)d_in[1];
  const float* value = (const float*)d_in[2];
  const float* cosT  = (const float*)d_in[4];
  const float* sinT  = (const float*)d_in[5];
  const float* Wq = (const float*)d_in[6];
  const float* bq = (const float*)d_in[7];
  const float* Wk = (const float*)d_in[8];
  const float* bk = (const float*)d_in[9];
  const float* Wv = (const float*)d_in[10];
  const float* bv = (const float*)d_in[11];
  const float* Wo = (const float*)d_in[12];
  const float* bo = (const float*)d_in[13];
  float* out = (float*)d_out;

  char* ws = (char*)d_ws;
  const size_t MB = 1048576;
  unsigned short* Xq  = (unsigned short*)(ws);
  unsigned short* Xk  = (unsigned short*)(ws + 16 * MB);
  unsigned short* Xv  = (unsigned short*)(ws + 32 * MB);
  unsigned short* Wqb = (unsigned short*)(ws + 48 * MB);
  unsigned short* Wkb = (unsigned short*)(ws + 56 * MB);
  unsigned short* Wvb = (unsigned short*)(ws + 64 * MB);
  unsigned short* Wob = (unsigned short*)(ws + 72 * MB);
  unsigned short* Qf  = (unsigned short*)(ws + 80 * MB);
  unsigned short* Kf  = (unsigned short*)(ws + 96 * MB);
  unsigned short* Vf  = (unsigned short*)(ws + 112 * MB);
  unsigned short* Qbb = Xq;
  unsigned short* Kbb = Xk;
  unsigned short* Vtb = Xv;
  unsigned short* Opb = (unsigned short*)(ws + 48 * MB);

  // 1. converts (coalesced: one float4/thread)
  CvtArgs ca;
  ca.s[0] = query; ca.d[0] = Xq;  ca.n4[0] = 2097152;
  ca.s[1] = key;   ca.d[1] = Xk;  ca.n4[1] = 2097152;
  ca.s[2] = value; ca.d[2] = Xv;  ca.n4[2] = 2097152;
  ca.s[3] = Wq;    ca.d[3] = Wqb; ca.n4[3] = 1048576;
  ca.s[4] = Wk;    ca.d[4] = Wkb; ca.n4[4] = 1048576;
  ca.s[5] = Wv;    ca.d[5] = Wvb; ca.n4[5] = 1048576;
  ca.s[6] = Wo;    ca.d[6] = Wob; ca.n4[6] = 1048576;
  cvtall<<<dim3(8192, 7), 256, 0, stream>>>(ca);

  // 2. Q,K,V projections: BM=256 (MF=8), 768 blocks of 256 thr, 2 blocks/CU
  GemmArgs gp;
  gp.A[0] = Xq;  gp.A[1] = Xk;  gp.A[2] = Xv;
  gp.W[0] = Wqb; gp.W[1] = Wkb; gp.W[2] = Wvb;
  gp.bias[0] = bq; gp.bias[1] = bk; gp.bias[2] = bv;
  gp.Cb[0] = Qf; gp.Cb[1] = Kf; gp.Cb[2] = Vf;
  gp.Cf = nullptr;
  gemm_bf16<true, 3, 8><<<768, 256, 73728, stream>>>(gp);

  // 3. rmsnorm+rope + V transpose (one dispatch)
  rmsvt<<<17408, 256, 0, stream>>>(Qf, Kf, Vf, cosT, sinT, Qbb, Kbb, Vtb);

  // 4. attention v3 (no split; fused normalize + v-projection removal)
  attn<<<256, 512, 83968, stream>>>(Qbb, Kbb, Vtb, Vf, Opb);

  // 5. output projection: BM=256 (MF=8), 256 blocks of 256 thr
  GemmArgs go;
  go.A[0] = Opb; go.A[1] = nullptr; go.A[2] = nullptr;
  go.W[0] = Wob; go.W[1] = nullptr; go.W[2] = nullptr;
  go.bias[0] = bo; go.bias[1] = nullptr; go.bias[2] = nullptr;
  go.Cb[0] = nullptr; go.Cb[1] = nullptr; go.Cb[2] = nullptr;
  go.Cf = out;
  gemm_bf16<false, 1, 8><<<256, 256, 73728, stream>>>(go);
}